// Round 1
// baseline (159.238 us; speedup 1.0000x reference)
//
#include <hip/hip_runtime.h>

#define TOTAL  4194304
#define DIM    32
#define NTOK   (TOTAL / DIM)   // 131072 tokens
#define NCODE  1024
#define CHUNK  256             // codes staged in LDS per pass

__global__ __launch_bounds__(256) void vq_argmin_kernel(
    const float* __restrict__ w,
    const float* __restrict__ c,
    const float* __restrict__ cb,
    int* __restrict__ out)
{
    __shared__ float se[CHUNK * DIM];   // 32 KB
    __shared__ float se2[CHUNK];        // 1 KB

    const int tid = threadIdx.x;
    const int t   = blockIdx.x * 256 + tid;   // token id, grid covers exactly NTOK

    // ---- load x = w - c  (32 consecutive floats per token), keep in VGPRs
    float x[DIM];
    const float4* w4 = reinterpret_cast<const float4*>(w) + (size_t)t * 8;
    const float4* c4 = reinterpret_cast<const float4*>(c) + (size_t)t * 8;
#pragma unroll
    for (int j = 0; j < 8; ++j) {
        float4 a = w4[j];
        float4 b = c4[j];
        x[4 * j + 0] = a.x - b.x;
        x[4 * j + 1] = a.y - b.y;
        x[4 * j + 2] = a.z - b.z;
        x[4 * j + 3] = a.w - b.w;
    }

    // ---- |x|^2 (per-token constant; fp32 sequential fma)
    float x2 = 0.0f;
#pragma unroll
    for (int i = 0; i < DIM; ++i) x2 = fmaf(x[i], x[i], x2);

    float dmin = INFINITY;
    int   best = 0;

    for (int c0 = 0; c0 < NCODE; c0 += CHUNK) {
        __syncthreads();   // protect previous chunk's readers
        // ---- stage chunk: thread tid owns code (c0 + tid): 32 floats + |e|^2
        {
            const float4* e4 = reinterpret_cast<const float4*>(cb) + (size_t)(c0 + tid) * 8;
            float4 v[8];
#pragma unroll
            for (int j = 0; j < 8; ++j) v[j] = e4[j];
            float e2 = 0.0f;
#pragma unroll
            for (int j = 0; j < 8; ++j) {
                e2 = fmaf(v[j].x, v[j].x, e2);
                e2 = fmaf(v[j].y, v[j].y, e2);
                e2 = fmaf(v[j].z, v[j].z, e2);
                e2 = fmaf(v[j].w, v[j].w, e2);
            }
            float4* dst = reinterpret_cast<float4*>(&se[tid * DIM]);
#pragma unroll
            for (int j = 0; j < 8; ++j) dst[j] = v[j];
            se2[tid] = e2;
        }
        __syncthreads();

        // ---- scan chunk: wave-uniform LDS reads (broadcast)
        for (int kk = 0; kk < CHUNK; ++kk) {
            const float* e = &se[kk * DIM];
            float acc = 0.0f;
#pragma unroll
            for (int i = 0; i < DIM; ++i) acc = fmaf(x[i], e[i], acc);
            // d = (x2 - 2*dot) + e2  -- same expression shape as the reference
            float d = fmaf(-2.0f, acc, x2) + se2[kk];
            int k = c0 + kk;
            if (d < dmin) { dmin = d; best = k; }   // strict <  => first-min tie-break
        }
    }

    out[t] = best;
}

extern "C" void kernel_launch(void* const* d_in, const int* in_sizes, int n_in,
                              void* d_out, int out_size, void* d_ws, size_t ws_size,
                              hipStream_t stream) {
    const float* w  = (const float*)d_in[0];   // weights  [4194304]
    const float* c  = (const float*)d_in[1];   // condition [1,32,131072] flat
    const float* cb = (const float*)d_in[2];   // codebook [1024,32]
    int* out = (int*)d_out;                    // int32 indices [131072]

    dim3 grid(NTOK / 256);   // 512 blocks
    dim3 block(256);
    vq_argmin_kernel<<<grid, block, 0, stream>>>(w, c, cb, out);
}